// Round 4
// baseline (69.197 us; speedup 1.0000x reference)
//
#include <hip/hip_runtime.h>
#include <math.h>

// PhaseLoss: ip + gd + ptd phase losses over [32,1,513,512] fp32 spectra.
// d'[b,f,t] = angle(ref * conj(est)); ip = |d'|;
// gd  = unwrap(d'[f-1,t] - d'[f,t])  (f-1<0 -> 0)
// ptd = unwrap(d'[f,t-1] - d'[f,t])  (t-1<0 -> 0)
// out = sum / (B*F*T)
//
// Structure: register-carried f-loop, RPW=4 rows per wave (+1 recomputed halo
// row). 4128 waves / 1032 blocks -> 4 waves/SIMD for latency hiding.
// t-neighbor = register/shfl_up; f-neighbor = previous iteration's registers.
// Finalize fused: slots + device-scope atomic counter; last finished block
// sums all slots and writes the scalar. Counter zeroed via 4B memsetAsync.

#define NB 32
#define NF 513
#define NT 512
#define RPW 4
#define CHUNKS 129         // ceil(513/4)
#define NBLOCKS 1032       // 32*129 waves / 4 waves per block
#define NTOT 8404992LL     // 32*513*512

static __device__ __forceinline__ float fast_atan2(float y, float x) {
    const float PI_F  = 3.14159274101257324f;
    const float PI_2F = 1.57079632679489662f;
    float ax = fabsf(x), ay = fabsf(y);
    float mx = fmaxf(ax, ay), mn = fminf(ax, ay);
    float r  = mn * __builtin_amdgcn_rcpf(mx);
    r = (mx == 0.f) ? 0.f : r;
    float s = r * r;
    float p = fmaf(s, -0.01172120f, 0.05265332f);
    p = fmaf(s, p, -0.11643287f);
    p = fmaf(s, p,  0.19354346f);
    p = fmaf(s, p, -0.33262347f);
    p = fmaf(s, p,  0.99997726f);
    float a = r * p;
    a = (ay > ax) ? (PI_2F - a) : a;
    a = (x < 0.f) ? (PI_F - a) : a;
    return copysignf(a, y);
}

static __device__ __forceinline__ float pdiff(float a, float b, float c, float d) {
    // est=a+ib, ref=c+id: angle(ref*conj(est)) = atan2(d*a - c*b, c*a + d*b)
    return fast_atan2(fmaf(d, a, -(c * b)), fmaf(c, a, d * b));
}

static __device__ __forceinline__ float wrap_abs(float x) {
    const float PI_F     = 3.14159274101257324f;
    const float TWO_PI_F = 6.28318548202514648f;
    float u = fabsf(x);
    return u > PI_F ? TWO_PI_F - u : u;
}

struct Row8 { float4 a0, a1, b0, b1, c0, c1, e0, e1; };

static __device__ __forceinline__ void calc8(const Row8& r, float d[8]) {
    d[0] = pdiff(r.a0.x, r.b0.x, r.c0.x, r.e0.x);
    d[1] = pdiff(r.a0.y, r.b0.y, r.c0.y, r.e0.y);
    d[2] = pdiff(r.a0.z, r.b0.z, r.c0.z, r.e0.z);
    d[3] = pdiff(r.a0.w, r.b0.w, r.c0.w, r.e0.w);
    d[4] = pdiff(r.a1.x, r.b1.x, r.c1.x, r.e1.x);
    d[5] = pdiff(r.a1.y, r.b1.y, r.c1.y, r.e1.y);
    d[6] = pdiff(r.a1.z, r.b1.z, r.c1.z, r.e1.z);
    d[7] = pdiff(r.a1.w, r.b1.w, r.c1.w, r.e1.w);
}

__global__ __launch_bounds__(256) void phase_loss_k(
    const float* __restrict__ er, const float* __restrict__ ei,
    const float* __restrict__ rr, const float* __restrict__ ri,
    float* __restrict__ slots, unsigned* __restrict__ cnt,
    float* __restrict__ out)
{
    const int tid  = threadIdx.x;
    const int lane = tid & 63;
    const int wid  = (blockIdx.x << 2) | (tid >> 6);   // 0..4127
    const int b    = wid / CHUNKS;
    const int f0   = (wid - b * CHUNKS) * RPW;
    const int base = b * (NF * NT);

#define LOAD_ROW(dst, f_) do {                                   \
        const int _i = base + (f_) * NT + lane * 8;              \
        dst.a0 = *(const float4*)(er + _i);                      \
        dst.a1 = *(const float4*)(er + _i + 4);                  \
        dst.b0 = *(const float4*)(ei + _i);                      \
        dst.b1 = *(const float4*)(ei + _i + 4);                  \
        dst.c0 = *(const float4*)(rr + _i);                      \
        dst.c1 = *(const float4*)(rr + _i + 4);                  \
        dst.e0 = *(const float4*)(ri + _i);                      \
        dst.e1 = *(const float4*)(ri + _i + 4);                  \
    } while (0)

    float s = 0.f;
    float dp[8];
    Row8 cur, nxt;

    if (f0 > 0) LOAD_ROW(cur, f0 - 1);       // halo row (recompute, L2-hot)
    LOAD_ROW(nxt, f0);                        // first owned row (prefetch)
    if (f0 > 0) {
        calc8(cur, dp);
    } else {
        #pragma unroll
        for (int k = 0; k < 8; ++k) dp[k] = 0.f;
    }

    #pragma unroll
    for (int r = 0; r < RPW; ++r) {
        const int f = f0 + r;
        if (f >= NF) break;                   // wave-uniform
        cur = nxt;
        if (r + 1 < RPW && f + 1 < NF) LOAD_ROW(nxt, f + 1);  // prefetch next row
        float d[8];
        calc8(cur, d);
        float dt = __shfl_up(d[7], 1, 64);
        if (lane == 0) dt = 0.f;              // t==0 neighbor
        #pragma unroll
        for (int k = 0; k < 8; ++k) {
            s += fabsf(d[k]);                 // ip
            s += wrap_abs(dp[k] - d[k]);      // gd
            s += wrap_abs(dt - d[k]);         // ptd
            dt = d[k];
            dp[k] = d[k];
        }
    }
#undef LOAD_ROW

    // block reduction
    #pragma unroll
    for (int off = 32; off > 0; off >>= 1)
        s += __shfl_down(s, off, 64);
    __shared__ float ws4[4];
    __shared__ unsigned last_flag;
    if (lane == 0) ws4[tid >> 6] = s;
    __syncthreads();
    if (tid == 0) {
        slots[blockIdx.x] = ws4[0] + ws4[1] + ws4[2] + ws4[3];
        __threadfence();                      // publish slot (device scope)
        unsigned prev = atomicAdd(cnt, 1u);   // device-scope by default
        last_flag = (prev == NBLOCKS - 1) ? 1u : 0u;
    }
    __syncthreads();

    if (last_flag) {                          // last block finalizes
        __threadfence();                      // acquire side
        float t = 0.f;
        for (int i = tid; i < NBLOCKS; i += 256) t += slots[i];
        #pragma unroll
        for (int off = 32; off > 0; off >>= 1)
            t += __shfl_down(t, off, 64);
        __shared__ float fs4[4];
        if (lane == 0) fs4[tid >> 6] = t;
        __syncthreads();
        if (tid == 0) {
            double tot = (double)fs4[0] + (double)fs4[1] + (double)fs4[2] + (double)fs4[3];
            out[0] = (float)(tot / (double)NTOT);
        }
    }
}

extern "C" void kernel_launch(void* const* d_in, const int* in_sizes, int n_in,
                              void* d_out, int out_size, void* d_ws, size_t ws_size,
                              hipStream_t stream) {
    const float* er = (const float*)d_in[0];
    const float* ei = (const float*)d_in[1];
    const float* rr = (const float*)d_in[2];
    const float* ri = (const float*)d_in[3];
    float* out   = (float*)d_out;
    float* slots = (float*)d_ws;                         // NBLOCKS fp32
    unsigned* cnt = (unsigned*)((char*)d_ws + NBLOCKS * sizeof(float));

    hipMemsetAsync(cnt, 0, sizeof(unsigned), stream);    // counter must start at 0

    phase_loss_k<<<NBLOCKS, 256, 0, stream>>>(er, ei, rr, ri, slots, cnt, out);
}

// Round 5
// 35.154 us; speedup vs baseline: 1.9684x; 1.9684x over previous
//
#include <hip/hip_runtime.h>
#include <math.h>

// PhaseLoss: ip + gd + ptd phase losses over [32,1,513,512] fp32 spectra.
// d'[b,f,t] = angle(ref * conj(est)); ip = |d'|;
// gd  = unwrap(d'[f-1,t] - d'[f,t])  (f-1<0 -> 0)
// ptd = unwrap(d'[f,t-1] - d'[f,t])  (t-1<0 -> 0)
// out = sum / (B*F*T)
//
// Structure: register-carried f-loop, RPW=4 rows/wave (+1 recomputed halo row).
// 4128 waves / 1032 blocks -> ~4 waves/SIMD. t-neighbor = shfl_up; f-neighbor =
// previous iteration's registers. No LDS staging, no atomics, NO threadfence
// (R4 lesson: device-scope fence = per-block L2 invalidate on gfx950, kills
// the memory path). Separate finalize kernel; kernel boundary = visibility.

#define NB 32
#define NF 513
#define NT 512
#define RPW 4
#define CHUNKS 129         // ceil(513/4)
#define NBLOCKS 1032       // 32*129 waves / 4 waves per block
#define NTOT 8404992LL     // 32*513*512

static __device__ __forceinline__ float fast_atan2(float y, float x) {
    const float PI_F  = 3.14159274101257324f;
    const float PI_2F = 1.57079632679489662f;
    float ax = fabsf(x), ay = fabsf(y);
    float mx = fmaxf(ax, ay), mn = fminf(ax, ay);
    float r  = mn * __builtin_amdgcn_rcpf(mx);
    r = (mx == 0.f) ? 0.f : r;
    float s = r * r;
    float p = fmaf(s, -0.01172120f, 0.05265332f);
    p = fmaf(s, p, -0.11643287f);
    p = fmaf(s, p,  0.19354346f);
    p = fmaf(s, p, -0.33262347f);
    p = fmaf(s, p,  0.99997726f);
    float a = r * p;
    a = (ay > ax) ? (PI_2F - a) : a;
    a = (x < 0.f) ? (PI_F - a) : a;
    return copysignf(a, y);
}

static __device__ __forceinline__ float pdiff(float a, float b, float c, float d) {
    // est=a+ib, ref=c+id: angle(ref*conj(est)) = atan2(d*a - c*b, c*a + d*b)
    return fast_atan2(fmaf(d, a, -(c * b)), fmaf(c, a, d * b));
}

static __device__ __forceinline__ float wrap_abs(float x) {
    const float PI_F     = 3.14159274101257324f;
    const float TWO_PI_F = 6.28318548202514648f;
    float u = fabsf(x);
    return u > PI_F ? TWO_PI_F - u : u;
}

struct Row8 { float4 a0, a1, b0, b1, c0, c1, e0, e1; };

static __device__ __forceinline__ void calc8(const Row8& r, float d[8]) {
    d[0] = pdiff(r.a0.x, r.b0.x, r.c0.x, r.e0.x);
    d[1] = pdiff(r.a0.y, r.b0.y, r.c0.y, r.e0.y);
    d[2] = pdiff(r.a0.z, r.b0.z, r.c0.z, r.e0.z);
    d[3] = pdiff(r.a0.w, r.b0.w, r.c0.w, r.e0.w);
    d[4] = pdiff(r.a1.x, r.b1.x, r.c1.x, r.e1.x);
    d[5] = pdiff(r.a1.y, r.b1.y, r.c1.y, r.e1.y);
    d[6] = pdiff(r.a1.z, r.b1.z, r.c1.z, r.e1.z);
    d[7] = pdiff(r.a1.w, r.b1.w, r.c1.w, r.e1.w);
}

__global__ __launch_bounds__(256) void phase_loss_k(
    const float* __restrict__ er, const float* __restrict__ ei,
    const float* __restrict__ rr, const float* __restrict__ ri,
    float* __restrict__ slots)
{
    const int tid  = threadIdx.x;
    const int lane = tid & 63;
    const int wid  = (blockIdx.x << 2) | (tid >> 6);   // 0..4127
    const int b    = wid / CHUNKS;
    const int f0   = (wid - b * CHUNKS) * RPW;
    const int base = b * (NF * NT);

#define LOAD_ROW(dst, f_) do {                                   \
        const int _i = base + (f_) * NT + lane * 8;              \
        dst.a0 = *(const float4*)(er + _i);                      \
        dst.a1 = *(const float4*)(er + _i + 4);                  \
        dst.b0 = *(const float4*)(ei + _i);                      \
        dst.b1 = *(const float4*)(ei + _i + 4);                  \
        dst.c0 = *(const float4*)(rr + _i);                      \
        dst.c1 = *(const float4*)(rr + _i + 4);                  \
        dst.e0 = *(const float4*)(ri + _i);                      \
        dst.e1 = *(const float4*)(ri + _i + 4);                  \
    } while (0)

    float s = 0.f;
    float dp[8];
    Row8 cur, nxt;

    if (f0 > 0) LOAD_ROW(cur, f0 - 1);       // halo row (recompute, L2-hot)
    LOAD_ROW(nxt, f0);                        // first owned row (prefetch)
    if (f0 > 0) {
        calc8(cur, dp);
    } else {
        #pragma unroll
        for (int k = 0; k < 8; ++k) dp[k] = 0.f;
    }

    #pragma unroll
    for (int r = 0; r < RPW; ++r) {
        const int f = f0 + r;
        if (f >= NF) break;                   // wave-uniform
        cur = nxt;
        if (r + 1 < RPW && f + 1 < NF) LOAD_ROW(nxt, f + 1);  // prefetch next row
        float d[8];
        calc8(cur, d);
        float dt = __shfl_up(d[7], 1, 64);
        if (lane == 0) dt = 0.f;              // t==0 neighbor
        #pragma unroll
        for (int k = 0; k < 8; ++k) {
            s += fabsf(d[k]);                 // ip
            s += wrap_abs(dp[k] - d[k]);      // gd
            s += wrap_abs(dt - d[k]);         // ptd
            dt = d[k];
            dp[k] = d[k];
        }
    }
#undef LOAD_ROW

    // per-wave reduce, tiny cross-wave combine, one plain store per block
    #pragma unroll
    for (int off = 32; off > 0; off >>= 1)
        s += __shfl_down(s, off, 64);
    __shared__ float ws4[4];
    if (lane == 0) ws4[tid >> 6] = s;
    __syncthreads();
    if (tid == 0) slots[blockIdx.x] = ws4[0] + ws4[1] + ws4[2] + ws4[3];
}

__global__ __launch_bounds__(256) void finalize_k(const float* __restrict__ slots,
                                                  float* __restrict__ out)
{
    int tid = threadIdx.x;
    float s = 0.f;
    for (int i = tid; i < NBLOCKS; i += 256) s += slots[i];
    #pragma unroll
    for (int off = 32; off > 0; off >>= 1)
        s += __shfl_down(s, off, 64);
    __shared__ float wsum[4];
    if ((tid & 63) == 0) wsum[tid >> 6] = s;
    __syncthreads();
    if (tid == 0) {
        double tot = (double)wsum[0] + (double)wsum[1] + (double)wsum[2] + (double)wsum[3];
        out[0] = (float)(tot / (double)NTOT);
    }
}

extern "C" void kernel_launch(void* const* d_in, const int* in_sizes, int n_in,
                              void* d_out, int out_size, void* d_ws, size_t ws_size,
                              hipStream_t stream) {
    const float* er = (const float*)d_in[0];
    const float* ei = (const float*)d_in[1];
    const float* rr = (const float*)d_in[2];
    const float* ri = (const float*)d_in[3];
    float* out   = (float*)d_out;
    float* slots = (float*)d_ws;              // NBLOCKS fp32, fully rewritten each call

    phase_loss_k<<<NBLOCKS, 256, 0, stream>>>(er, ei, rr, ri, slots);
    finalize_k<<<1, 256, 0, stream>>>(slots, out);
}